// Round 3
// baseline (196.642 us; speedup 1.0000x reference)
//
#include <hip/hip_runtime.h>

// Problem constants (fixed by the reference): N=262144, D=256, B=512, M=1024.
#define FEAT_D   256
#define MAX_M    1024
#define NSETS    512

typedef float f4 __attribute__((ext_vector_type(4)));

// starts[b] = first index i with batch[i] >= b  (batch is sorted ascending).
__global__ void k_starts(const int* __restrict__ batch, int n,
                         int* __restrict__ starts) {
    int b = blockIdx.x * blockDim.x + threadIdx.x;
    if (b > NSETS) return;
    int lo = 0, hi = n;
    while (lo < hi) {
        int mid = (lo + hi) >> 1;
        if (batch[mid] < b) lo = mid + 1; else hi = mid;
    }
    starts[b] = lo;
}

// One block = one quarter of one set (256 rows). 2048 blocks total.
// Each wave owns 64 consecutive rows; lane l moves float4 #l of each row
// (64 lanes * 16B = one full 1KB row per iteration, perfectly coalesced).
// starts[] is read once per thread (was: twice per float4 moved).
// Unrolled loop gives 8 nontemporal loads in flight before the stores.
__global__ void __launch_bounds__(256)
k_gather(const f4* __restrict__ src4,
         const int* __restrict__ starts,
         f4* __restrict__ out4,
         f4* __restrict__ mask4) {
    int b = blockIdx.x >> 2;          // set id
    int q = blockIdx.x & 3;           // quarter within set
    int wave = threadIdx.x >> 6;
    int lane = threadIdx.x & 63;
    int s   = starts[b];
    int cnt = starts[b + 1] - s;

    int r0 = q * 256 + wave * 64;     // first row this wave handles
    const f4* ip = src4 + ((size_t)s + r0) * (FEAT_D / 4) + lane;
    f4*       op = out4 + (((size_t)b << 10) + r0) * (FEAT_D / 4) + lane;

    #pragma unroll 8
    for (int j = 0; j < 64; ++j) {
        f4 v = (f4)(0.0f);
        if (r0 + j < cnt)
            v = __builtin_nontemporal_load(ip + (size_t)j * (FEAT_D / 4));
        __builtin_nontemporal_store(v, op + (size_t)j * (FEAT_D / 4));
    }

    // Mask for set b: 1024 floats = 256 float4s, written by quarter-0 block.
    if (q == 0) {
        int t = threadIdx.x;          // 0..255
        f4 mv;
        mv[0] = (4 * t + 0) < cnt ? 1.0f : 0.0f;
        mv[1] = (4 * t + 1) < cnt ? 1.0f : 0.0f;
        mv[2] = (4 * t + 2) < cnt ? 1.0f : 0.0f;
        mv[3] = (4 * t + 3) < cnt ? 1.0f : 0.0f;
        __builtin_nontemporal_store(mv, &mask4[((size_t)b << 8) + t]);
    }
}

extern "C" void kernel_launch(void* const* d_in, const int* in_sizes, int n_in,
                              void* d_out, int out_size, void* d_ws, size_t ws_size,
                              hipStream_t stream) {
    const float* src   = (const float*)d_in[0];
    const int*   batch = (const int*)d_in[1];   // harness delivers ints as int32
    int n = in_sizes[1];                        // N ragged elements

    int* starts = (int*)d_ws;                   // (NSETS+1) ints

    // 1) segment starts via binary search (513 threads, trivial cost)
    k_starts<<<(NSETS + 1 + 255) / 256, 256, 0, stream>>>(batch, n, starts);

    // 2) padded gather + fused mask: 4 blocks per set
    f4* mask4 = (f4*)((float*)d_out + (size_t)NSETS * MAX_M * FEAT_D);
    k_gather<<<NSETS * 4, 256, 0, stream>>>(
        (const f4*)src, starts, (f4*)d_out, mask4);
}

// Round 4
// 158.434 us; speedup vs baseline: 1.2412x; 1.2412x over previous
//
#include <hip/hip_runtime.h>

// Problem constants (fixed by the reference): N=262144, D=256, B=512, M=1024.
#define FEAT_D   256
#define MAX_M    1024
#define NSETS    512

typedef float f4 __attribute__((ext_vector_type(4)));

// starts[b] = first index i with batch[i] >= b  (batch is sorted ascending).
__global__ void k_starts(const int* __restrict__ batch, int n,
                         int* __restrict__ starts) {
    int b = blockIdx.x * blockDim.x + threadIdx.x;
    if (b > NSETS) return;
    int lo = 0, hi = n;
    while (lo < hi) {
        int mid = (lo + hi) >> 1;
        if (batch[mid] < b) lo = mid + 1; else hi = mid;
    }
    starts[b] = lo;
}

// R2 structure (best so far): one output row (b,m) per 64-lane wave, one
// float4 per lane, 131072 independent blocks of 4 rows -> max MLP.
// Change vs R2: stores are PLAIN (not nontemporal). The harness fill kernels
// (plain stores) hit 6.7 TB/s write-only vs our 5.3 TB/s aggregate -> let
// L2/L3 buffer the write stream. Loads stay nontemporal (zero-reuse read
// stream must not pollute the cache against the writes).
__global__ void __launch_bounds__(256)
k_gather(const f4* __restrict__ src4,
         const int* __restrict__ starts,
         f4* __restrict__ out4,
         float* __restrict__ mask) {
    int tid  = blockIdx.x * blockDim.x + threadIdx.x;
    int row  = tid >> 6;        // 64 lanes per output row
    int lane = tid & 63;
    int b = row >> 10;          // row / MAX_M
    int m = row & (MAX_M - 1);
    int s   = starts[b];
    int cnt = starts[b + 1] - s;
    f4 v = (f4)(0.0f);
    bool valid = (m < cnt);
    if (valid)
        v = __builtin_nontemporal_load(&src4[(size_t)(s + m) * (FEAT_D / 4) + lane]);
    out4[(size_t)row * (FEAT_D / 4) + lane] = v;
    if (lane == 0)
        mask[row] = valid ? 1.0f : 0.0f;
}

extern "C" void kernel_launch(void* const* d_in, const int* in_sizes, int n_in,
                              void* d_out, int out_size, void* d_ws, size_t ws_size,
                              hipStream_t stream) {
    const float* src   = (const float*)d_in[0];
    const int*   batch = (const int*)d_in[1];   // harness delivers ints as int32
    int n = in_sizes[1];                        // N ragged elements

    int* starts = (int*)d_ws;                   // (NSETS+1) ints

    // 1) segment starts via binary search (513 threads, trivial cost)
    k_starts<<<(NSETS + 1 + 255) / 256, 256, 0, stream>>>(batch, n, starts);

    // 2) padded gather + fused mask: B*M rows, 4 rows per 256-thread block
    int total_rows = NSETS * MAX_M;             // 524288
    float* mask = (float*)d_out + (size_t)NSETS * MAX_M * FEAT_D;
    k_gather<<<total_rows / 4, 256, 0, stream>>>(
        (const f4*)src, starts, (f4*)d_out, mask);
}

// Round 6
// 148.809 us; speedup vs baseline: 1.3214x; 1.0647x over previous
//
#include <hip/hip_runtime.h>

// Problem constants (fixed by the reference): N=262144, D=256, B=512, M=1024.
#define FEAT_D   256
#define MAX_M    1024
#define NSETS    512

typedef float f4 __attribute__((ext_vector_type(4)));
typedef float f2 __attribute__((ext_vector_type(2)));

// sc[b] = (start, count) for set b via two binary searches (batch sorted).
__global__ void k_starts(const int* __restrict__ batch, int n,
                         int2* __restrict__ sc) {
    int b = blockIdx.x * blockDim.x + threadIdx.x;
    if (b >= NSETS) return;
    int lo = 0, hi = n;
    while (lo < hi) { int mid = (lo + hi) >> 1; if (batch[mid] < b) lo = mid + 1; else hi = mid; }
    int lo2 = lo, hi2 = n;      // lower_bound(b+1), search range [lo, n)
    while (lo2 < hi2) { int mid = (lo2 + hi2) >> 1; if (batch[mid] < b + 1) lo2 = mid + 1; else hi2 = mid; }
    sc[b] = make_int2(lo, lo2 - lo);
}

// R2 structure + two upgrades:
//  - (start,count) fetched once per block via readfirstlane -> scalar load
//    (b is block-uniform: blocks cover 8 consecutive rows, 1024 % 8 == 0).
//  - each wave owns 2 consecutive rows: 2 independent nt loads in flight,
//    then 2 nt stores; address streams identical to R2, half the workgroups.
// nt on both loads and stores (best policy per R2 vs R1/R4 A/B).
__global__ void __launch_bounds__(256)
k_gather(const f4* __restrict__ src4,
         const int2* __restrict__ sc,
         f4* __restrict__ out4,
         f2* __restrict__ mask2) {
    int tid  = blockIdx.x * blockDim.x + threadIdx.x;
    int pair = tid >> 6;              // wave id = pair of rows
    int lane = tid & 63;
    int row0 = pair << 1;             // first of the 2 rows
    int b = __builtin_amdgcn_readfirstlane(row0 >> 10);
    int2 s_c = sc[b];                 // uniform address -> s_load
    int s = s_c.x, cnt = s_c.y;
    int m0 = row0 & (MAX_M - 1);
    bool v0 = (m0 < cnt), v1 = (m0 + 1 < cnt);   // wave-uniform
    f4 a0 = (f4)(0.0f), a1 = (f4)(0.0f);
    const f4* ip = src4 + ((size_t)s + m0) * (FEAT_D / 4) + lane;
    if (v0) a0 = __builtin_nontemporal_load(ip);
    if (v1) a1 = __builtin_nontemporal_load(ip + (FEAT_D / 4));
    f4* op = out4 + (size_t)row0 * (FEAT_D / 4) + lane;
    __builtin_nontemporal_store(a0, op);
    __builtin_nontemporal_store(a1, op + (FEAT_D / 4));
    if (lane == 0) {
        f2 mv;
        mv[0] = v0 ? 1.0f : 0.0f;
        mv[1] = v1 ? 1.0f : 0.0f;
        __builtin_nontemporal_store(mv, &mask2[pair]);
    }
}

extern "C" void kernel_launch(void* const* d_in, const int* in_sizes, int n_in,
                              void* d_out, int out_size, void* d_ws, size_t ws_size,
                              hipStream_t stream) {
    const float* src   = (const float*)d_in[0];
    const int*   batch = (const int*)d_in[1];   // harness delivers ints as int32
    int n = in_sizes[1];                        // N ragged elements

    int2* sc = (int2*)d_ws;                     // NSETS (start,count) pairs

    // 1) segment (start,count) via binary search (512 threads, trivial cost)
    k_starts<<<(NSETS + 255) / 256, 256, 0, stream>>>(batch, n, sc);

    // 2) padded gather + fused mask: 2 rows per wave, 8 rows per block
    int total_rows = NSETS * MAX_M;             // 524288
    f2* mask2 = (f2*)((float*)d_out + (size_t)NSETS * MAX_M * FEAT_D);
    k_gather<<<total_rows / 8, 256, 0, stream>>>(
        (const f4*)src, sc, (f4*)d_out, mask2);
}